// Round 5
// baseline (1165.505 us; speedup 1.0000x reference)
//
#include <hip/hip_runtime.h>
#include <math.h>

// DeepseekV2 MoE gate, MI355X — fp32 GEMM + margin-gated fp64 exact repair.
//
// Pass 1 (all tokens): fp32 logits = X[16384,5120] @ W[160,5120]^T, rank on
//   raw logits (monotone == score order when margins are wide), write outputs.
// Flag a token if ANY decision margin < TH=3e-4 (fp32 GEMM error ~4e-6 sigma):
//   - gap between 3rd and 4th group max (group-set decision)
//   - adjacent gaps among expert ranks 1..7 within allowed groups
//     (order of top-6 + membership at rank 6/7)
// Pass 2 (flagged tokens only, ~1-2%): recompute that token's 160 logits with
//   fp64 accumulation (exact to ~1e-12), cast to fp32, and re-run the proven
//   round-4 epilogue (fp32 softmax emulation, rank on scores, stable ties ->
//   lower index). This reproduces the reference's fp32-tie behavior exactly.

#define TT    16384
#define HH    5120
#define EE    160
#define BT    32         // tokens per block
#define BK    32         // K tile
#define NT    (HH / BK)  // 160
#define SXLD  36         // x LDS stride (floats): keeps 16B-aligned b128 reads
#define SWLD  161        // w LDS stride (floats): (k+e)%32 -> conflict-free
#define SLF   161        // fp32 logit LDS stride (floats)
#define TOPK  6
#define TH    3e-4f      // decision-margin threshold (~70 sigma of fp32 error)

__device__ __forceinline__ bool betterf(float va, int ia, float vb, int ib) {
    return (va > vb) || ((va == vb) && (ia < ib));
}

__global__ __launch_bounds__(256)
void gate_kernel(const float* __restrict__ X, const float* __restrict__ W,
                 float* __restrict__ out) {
    // GEMM staging: 2*32*36*4 + 2*32*161*4 = 50432 B.
    // Epilogue reuses the same bytes as [32][161] fp32 logits (20608 B).
    __shared__ __align__(16) unsigned char smem_raw[2*BK*SXLD*4 + 2*BK*SWLD*4];
    __shared__ int sFlags[BT];
    float* sx    = (float*)smem_raw;            // [2][BK][SXLD]  x^T: [k][tok]
    float* sw    = sx + 2 * BK * SXLD;          // [2][BK][SWLD]  w^T: [k][e]
    float* slogf = (float*)smem_raw;            // [BT][SLF]      fp32 logits

    const int tid = threadIdx.x;
    const int tx  = tid & 31;                   // experts {tx+32m}
    const int ty  = tid >> 5;                   // tokens  {4ty..4ty+3}
    const long tok0 = (long)blockIdx.x * BT;

    float acc[4][5];
    #pragma unroll
    for (int j = 0; j < 4; ++j)
        #pragma unroll
        for (int m = 0; m < 5; ++m) acc[j][m] = 0.f;

    float4 px, pw[5];

    // ---- prologue: tile 0 -> regs -> LDS buf0
    {
        int i = tid, tl = i >> 3, k4 = (i & 7) << 2;
        px = *(const float4*)(X + (tok0 + tl) * HH + k4);
        #pragma unroll
        for (int r = 0; r < 5; ++r) {
            int q = tid + 256 * r, e = q >> 3, kk = (q & 7) << 2;
            pw[r] = *(const float4*)(W + (long)e * HH + kk);
        }
        sx[(k4 + 0) * SXLD + tl] = px.x;
        sx[(k4 + 1) * SXLD + tl] = px.y;
        sx[(k4 + 2) * SXLD + tl] = px.z;
        sx[(k4 + 3) * SXLD + tl] = px.w;
        #pragma unroll
        for (int r = 0; r < 5; ++r) {
            int q = tid + 256 * r, e = q >> 3, kk = (q & 7) << 2;
            sw[(kk + 0) * SWLD + e] = pw[r].x;
            sw[(kk + 1) * SWLD + e] = pw[r].y;
            sw[(kk + 2) * SWLD + e] = pw[r].z;
            sw[(kk + 3) * SWLD + e] = pw[r].w;
        }
    }
    __syncthreads();

    // ---- main K loop: prefetch(t+1)->regs, fp32 compute(t), regs->LDS
    for (int t = 0; t < NT; ++t) {
        const int cur = t & 1;
        if (t + 1 < NT) {
            const int k0 = (t + 1) * BK;
            int i = tid, tl = i >> 3, k4 = (i & 7) << 2;
            px = *(const float4*)(X + (tok0 + tl) * HH + k0 + k4);
            #pragma unroll
            for (int r = 0; r < 5; ++r) {
                int q = tid + 256 * r, e = q >> 3, kk = (q & 7) << 2;
                pw[r] = *(const float4*)(W + (long)e * HH + k0 + kk);
            }
        }
        const float* bx = sx + cur * (BK * SXLD);
        const float* bw = sw + cur * (BK * SWLD);
        #pragma unroll 4
        for (int k = 0; k < BK; ++k) {
            float4 xa = *(const float4*)(bx + k * SXLD + 4 * ty);
            float wv[5];
            #pragma unroll
            for (int m = 0; m < 5; ++m) wv[m] = bw[k * SWLD + tx + 32 * m];
            float xv[4] = {xa.x, xa.y, xa.z, xa.w};
            #pragma unroll
            for (int j = 0; j < 4; ++j)
                #pragma unroll
                for (int m = 0; m < 5; ++m)
                    acc[j][m] = fmaf(xv[j], wv[m], acc[j][m]);
        }
        if (t + 1 < NT) {
            const int nb = (t + 1) & 1;
            float* wxp = sx + nb * (BK * SXLD);
            float* wwp = sw + nb * (BK * SWLD);
            int i = tid, tl = i >> 3, k4 = (i & 7) << 2;
            wxp[(k4 + 0) * SXLD + tl] = px.x;
            wxp[(k4 + 1) * SXLD + tl] = px.y;
            wxp[(k4 + 2) * SXLD + tl] = px.z;
            wxp[(k4 + 3) * SXLD + tl] = px.w;
            #pragma unroll
            for (int r = 0; r < 5; ++r) {
                int q = tid + 256 * r, e = q >> 3, kk = (q & 7) << 2;
                wwp[(kk + 0) * SWLD + e] = pw[r].x;
                wwp[(kk + 1) * SWLD + e] = pw[r].y;
                wwp[(kk + 2) * SWLD + e] = pw[r].z;
                wwp[(kk + 3) * SWLD + e] = pw[r].w;
            }
        }
        __syncthreads();
    }

    // ---- approx logits -> LDS
    #pragma unroll
    for (int j = 0; j < 4; ++j)
        #pragma unroll
        for (int m = 0; m < 5; ++m)
            slogf[(4 * ty + j) * SLF + tx + 32 * m] = acc[j][m];
    __syncthreads();

    // ==== provisional epilogue (rank on approx logits) + margin flags ====
    // 8 lanes/token; lane `sub` owns group `sub` = experts [20*sub, 20*sub+20)
    const int token = tid >> 3;
    const int sub   = tid & 7;
    {
        const float* rowp = slogf + token * SLF + sub * 20;
        float l[20];
        #pragma unroll
        for (int i = 0; i < 20; ++i) l[i] = rowp[i];

        // group max; row max; softmax denominator (for weights only)
        float gm = l[0];
        #pragma unroll
        for (int i = 1; i < 20; ++i) gm = fmaxf(gm, l[i]);
        float mx = gm;
        mx = fmaxf(mx, __shfl_xor(mx, 1));
        mx = fmaxf(mx, __shfl_xor(mx, 2));
        mx = fmaxf(mx, __shfl_xor(mx, 4));
        float sef = 0.f;
        #pragma unroll
        for (int i = 0; i < 20; ++i) sef += expf(l[i] - mx);
        sef += __shfl_xor(sef, 1);
        sef += __shfl_xor(sef, 2);
        sef += __shfl_xor(sef, 4);

        // gather 8 group maxes
        float a0 = gm;
        float a1 = __shfl_xor(a0, 1);
        float a2 = __shfl_xor(a0, 2), a3 = __shfl_xor(a1, 2);
        float a4 = __shfl_xor(a0, 4), a5 = __shfl_xor(a1, 4);
        float a6 = __shfl_xor(a2, 4), a7 = __shfl_xor(a3, 4);
        float gv[8] = {a0, a1, a2, a3, a4, a5, a6, a7};
        int   gi[8] = {sub, sub^1, sub^2, sub^3, sub^4, sub^5, sub^6, sub^7};

        // top-3 groups + the 3rd/4th gap (group-set decision margin)
        int tg0, tg1, tg2; float g3v, g4v;
        {
            float bv; int bi;
            bv = gv[0]; bi = gi[0];
            #pragma unroll
            for (int q = 1; q < 8; ++q) if (betterf(gv[q], gi[q], bv, bi)) { bv = gv[q]; bi = gi[q]; }
            tg0 = bi;
            #pragma unroll
            for (int q = 0; q < 8; ++q) if (gi[q] == tg0) gv[q] = -INFINITY;
            bv = gv[0]; bi = gi[0];
            #pragma unroll
            for (int q = 1; q < 8; ++q) if (betterf(gv[q], gi[q], bv, bi)) { bv = gv[q]; bi = gi[q]; }
            tg1 = bi;
            #pragma unroll
            for (int q = 0; q < 8; ++q) if (gi[q] == tg1) gv[q] = -INFINITY;
            bv = gv[0]; bi = gi[0];
            #pragma unroll
            for (int q = 1; q < 8; ++q) if (betterf(gv[q], gi[q], bv, bi)) { bv = gv[q]; bi = gi[q]; }
            tg2 = bi; g3v = bv;
            #pragma unroll
            for (int q = 0; q < 8; ++q) if (gi[q] == tg2) gv[q] = -INFINITY;
            bv = gv[0];
            #pragma unroll
            for (int q = 1; q < 8; ++q) bv = fmaxf(bv, gv[q]);
            g4v = bv;
        }
        const bool allowed = (sub == tg0) || (sub == tg1) || (sub == tg2);

        // lane-local top-7 of this lane's 20 logits (masked lanes -> -inf)
        float v[7]; int ix[7];
        #pragma unroll
        for (int j = 0; j < 7; ++j) { v[j] = -INFINITY; ix[j] = 1 << 30; }
        #pragma unroll
        for (int i = 0; i < 20; ++i) {
            const float val = allowed ? l[i] : -INFINITY;
            const int   idx = sub * 20 + i;
            if (betterf(val, idx, v[6], ix[6])) {
                v[6] = val; ix[6] = idx;
                #pragma unroll
                for (int j = 6; j >= 1; --j)
                    if (betterf(v[j], ix[j], v[j-1], ix[j-1])) {
                        float tv = v[j]; v[j] = v[j-1]; v[j-1] = tv;
                        int   ti = ix[j]; ix[j] = ix[j-1]; ix[j-1] = ti;
                    }
            }
        }
        // butterfly merge of top-7 across the 8 lanes
        #pragma unroll
        for (int st = 1; st <= 4; st <<= 1) {
            float pv[7]; int pix[7];
            #pragma unroll
            for (int j = 0; j < 7; ++j) {
                pv[j]  = __shfl_xor(v[j], st);
                pix[j] = __shfl_xor(ix[j], st);
            }
            #pragma unroll
            for (int j = 0; j < 7; ++j) {
                const float val = pv[j]; const int idx = pix[j];
                if (betterf(val, idx, v[6], ix[6])) {
                    v[6] = val; ix[6] = idx;
                    #pragma unroll
                    for (int q = 6; q >= 1; --q)
                        if (betterf(v[q], ix[q], v[q-1], ix[q-1])) {
                            float tv = v[q]; v[q] = v[q-1]; v[q-1] = tv;
                            int   ti = ix[q]; ix[q] = ix[q-1]; ix[q-1] = ti;
                        }
                }
            }
        }

        // decision margins
        float mingap = g3v - g4v;
        #pragma unroll
        for (int j = 0; j < 6; ++j) mingap = fminf(mingap, v[j] - v[j+1]);
        const int flag = (mingap < TH) ? 1 : 0;

        if (sub == 0) {
            sFlags[token] = flag;
            const long tokg = tok0 + token;
            #pragma unroll
            for (int j = 0; j < 6; ++j) {
                out[tokg * TOPK + j] = (float)ix[j];
                out[(long)TT * TOPK + tokg * TOPK + j] =
                    16.0f * expf(v[j] - mx) / sef;
            }
        }
    }
    __syncthreads();

    // ==== rare path: exact fp64 recompute of flagged tokens' logit rows ====
    for (int ft = 0; ft < BT; ++ft) {
        if (sFlags[ft] && tid < EE) {
            const float* xr = X + (tok0 + ft) * HH;
            const float* wr = W + (long)tid * HH;
            double c0 = 0.0, c1 = 0.0, c2 = 0.0, c3 = 0.0;
            for (int k = 0; k < HH; k += 4) {
                float4 xv = *(const float4*)(xr + k);
                float4 wv = *(const float4*)(wr + k);
                c0 = fma((double)xv.x, (double)wv.x, c0);
                c1 = fma((double)xv.y, (double)wv.y, c1);
                c2 = fma((double)xv.z, (double)wv.z, c2);
                c3 = fma((double)xv.w, (double)wv.w, c3);
            }
            slogf[ft * SLF + tid] = (float)((c0 + c1) + (c2 + c3));
        }
    }
    __syncthreads();

    // ==== exact epilogue for flagged tokens (round-4 proven path) ====
    if (sFlags[token]) {
        const float* rowp = slogf + token * SLF + sub * 20;
        float l[20];
        #pragma unroll
        for (int i = 0; i < 20; ++i) l[i] = rowp[i];

        float gm = l[0];
        #pragma unroll
        for (int i = 1; i < 20; ++i) gm = fmaxf(gm, l[i]);
        float mxf = gm;
        mxf = fmaxf(mxf, __shfl_xor(mxf, 1));
        mxf = fmaxf(mxf, __shfl_xor(mxf, 2));
        mxf = fmaxf(mxf, __shfl_xor(mxf, 4));

        #pragma unroll
        for (int i = 0; i < 20; ++i) l[i] = expf(l[i] - mxf);
        float sef = 0.f;
        #pragma unroll
        for (int i = 0; i < 20; ++i) sef += l[i];
        sef += __shfl_xor(sef, 1);
        sef += __shfl_xor(sef, 2);
        sef += __shfl_xor(sef, 4);
        #pragma unroll
        for (int i = 0; i < 20; ++i) l[i] = l[i] / sef;   // fp32 scores

        float gs = l[0];
        #pragma unroll
        for (int i = 1; i < 20; ++i) gs = fmaxf(gs, l[i]);

        float a0 = gs;
        float a1 = __shfl_xor(a0, 1);
        float a2 = __shfl_xor(a0, 2), a3 = __shfl_xor(a1, 2);
        float a4 = __shfl_xor(a0, 4), a5 = __shfl_xor(a1, 4);
        float a6 = __shfl_xor(a2, 4), a7 = __shfl_xor(a3, 4);
        float gv[8] = {a0, a1, a2, a3, a4, a5, a6, a7};
        int   gi[8] = {sub, sub^1, sub^2, sub^3, sub^4, sub^5, sub^6, sub^7};

        int tg0, tg1, tg2;
        {
            float bv; int bi;
            bv = gv[0]; bi = gi[0];
            #pragma unroll
            for (int q = 1; q < 8; ++q) if (betterf(gv[q], gi[q], bv, bi)) { bv = gv[q]; bi = gi[q]; }
            tg0 = bi;
            #pragma unroll
            for (int q = 0; q < 8; ++q) if (gi[q] == tg0) gv[q] = -INFINITY;
            bv = gv[0]; bi = gi[0];
            #pragma unroll
            for (int q = 1; q < 8; ++q) if (betterf(gv[q], gi[q], bv, bi)) { bv = gv[q]; bi = gi[q]; }
            tg1 = bi;
            #pragma unroll
            for (int q = 0; q < 8; ++q) if (gi[q] == tg1) gv[q] = -INFINITY;
            bv = gv[0]; bi = gi[0];
            #pragma unroll
            for (int q = 1; q < 8; ++q) if (betterf(gv[q], gi[q], bv, bi)) { bv = gv[q]; bi = gi[q]; }
            tg2 = bi;
        }
        const bool allowed = (sub == tg0) || (sub == tg1) || (sub == tg2);

        float v[6]; int ix[6];
        #pragma unroll
        for (int j = 0; j < 6; ++j) { v[j] = -INFINITY; ix[j] = 1 << 30; }
        #pragma unroll
        for (int i = 0; i < 20; ++i) {
            const float val = allowed ? l[i] : -INFINITY;
            const int   idx = sub * 20 + i;
            if (betterf(val, idx, v[5], ix[5])) {
                v[5] = val; ix[5] = idx;
                #pragma unroll
                for (int j = 5; j >= 1; --j)
                    if (betterf(v[j], ix[j], v[j-1], ix[j-1])) {
                        float tv = v[j]; v[j] = v[j-1]; v[j-1] = tv;
                        int   ti = ix[j]; ix[j] = ix[j-1]; ix[j-1] = ti;
                    }
            }
        }
        #pragma unroll
        for (int st = 1; st <= 4; st <<= 1) {
            float pv[6]; int pix[6];
            #pragma unroll
            for (int j = 0; j < 6; ++j) {
                pv[j]  = __shfl_xor(v[j], st);
                pix[j] = __shfl_xor(ix[j], st);
            }
            #pragma unroll
            for (int j = 0; j < 6; ++j) {
                const float val = pv[j]; const int idx = pix[j];
                if (betterf(val, idx, v[5], ix[5])) {
                    v[5] = val; ix[5] = idx;
                    #pragma unroll
                    for (int q = 5; q >= 1; --q)
                        if (betterf(v[q], ix[q], v[q-1], ix[q-1])) {
                            float tv = v[q]; v[q] = v[q-1]; v[q-1] = tv;
                            int   ti = ix[q]; ix[q] = ix[q-1]; ix[q-1] = ti;
                        }
                }
            }
        }

        if (sub == 0) {
            const long tokg = tok0 + token;
            #pragma unroll
            for (int j = 0; j < 6; ++j) {
                out[tokg * TOPK + j] = (float)ix[j];
                out[(long)TT * TOPK + tokg * TOPK + j] = 16.0f * v[j];
            }
        }
    }
}

extern "C" void kernel_launch(void* const* d_in, const int* in_sizes, int n_in,
                              void* d_out, int out_size, void* d_ws, size_t ws_size,
                              hipStream_t stream) {
    const float* X = (const float*)d_in[0];   // hidden_states [4,4096,5120] fp32
    const float* W = (const float*)d_in[1];   // weight [160,5120] fp32
    float* out = (float*)d_out;               // [idx: 98304][weight: 98304] fp32
    gate_kernel<<<TT / BT, 256, 0, stream>>>(X, W, out);
}